// Round 10
// baseline (224.096 us; speedup 1.0000x reference)
//
#include <hip/hip_runtime.h>

#define B_    64
#define HID_  4096
#define HQ_   32
#define HKV_  8
#define D_    128
#define BS_   16
#define MAXB_ 64

#define KS1     32                // K-split for both GEMMs
#define KCHUNK  (HID_ / KS1)      // 128
#define NSTEP   (KCHUNK / 32)     // 4
#define QKV_ROWS 6144             // 4096 q + 1024 k + 1024 v
#define O_ROWS   4096
#define SPLITS  8                 // flash-decode token splits

#define REGION_SZ ((size_t)KS1 * QKV_ROWS * 64)   // 12.6M floats, reused 3x
#define QKVF_SZ  ((size_t)64 * 6144)
#define XB_SZ    ((size_t)HID_ * 64)   // ushort count per XB buffer

typedef __attribute__((ext_vector_type(8))) short bf16x8;
typedef __attribute__((ext_vector_type(4))) float f32x4;

__device__ inline unsigned short f2bf(float x) {
  union { float f; unsigned u; } v; v.f = x;
  unsigned r = v.u + 0x7fff + ((v.u >> 16) & 1);   // RNE
  return (unsigned short)(r >> 16);
}
__device__ inline float bf2f(unsigned short h) {
  union { float f; unsigned u; } v; v.u = ((unsigned)h) << 16; return v.f;
}

// ---------------------------------------------------------------------------
// Convert X [64][HID] fp32 -> fragment-contiguous bf16 hi/lo:
// XB[kg][b][j] = bf16(X[b][kg*8+j]), j contiguous (16B per (kg,b)).
// ---------------------------------------------------------------------------
__global__ __launch_bounds__(256) void convert_x(
    const float* __restrict__ X, unsigned short* __restrict__ XBhi,
    unsigned short* __restrict__ XBlo)
{
  int idx = blockIdx.x * 256 + threadIdx.x;   // 0..32767
  int kg = idx >> 6, b = idx & 63;
  const float* xp = X + (size_t)b * HID_ + kg * 8;
  float4 a = *(const float4*)xp, c = *(const float4*)(xp + 4);
  float xs[8] = {a.x, a.y, a.z, a.w, c.x, c.y, c.z, c.w};
  unsigned short hi[8], lo[8];
  #pragma unroll
  for (int j = 0; j < 8; ++j) {
    hi[j] = f2bf(xs[j]);
    lo[j] = f2bf(xs[j] - bf2f(hi[j]));
  }
  *(uint4*)(XBhi + (size_t)idx * 8) = *(const uint4*)hi;
  *(uint4*)(XBlo + (size_t)idx * 8) = *(const uint4*)lo;
}

// ---------------------------------------------------------------------------
// Split-bf16 MFMA skinny GEMM partial (round-8 geometry, KS1=32):
// Wave = 32 rows (2 row-tiles) x 64 batches (4 B col-tiles of 16x16x32).
// A (W) fp32 direct from global (each byte once), cvt in-register to hi/lo;
// B from XB (L2-resident). 3 MFMA: hi*hi + lo*hi + hi*lo.
// part[ks][row][64batch].
// ---------------------------------------------------------------------------
__global__ __launch_bounds__(256, 4) void gemm_mfma(
    const float* __restrict__ W0, const float* __restrict__ W1,
    const float* __restrict__ W2,
    const unsigned short* __restrict__ XBhi,
    const unsigned short* __restrict__ XBlo,
    int split1, int split2, int rows_total, float* __restrict__ part)
{
  const int tid = threadIdx.x;
  const int l   = tid & 63;
  const int w   = tid >> 6;               // wave 0..3
  const int r0  = blockIdx.x * 128 + w * 32;
  const int k0  = blockIdx.y * KCHUNK;

  const float* W; int rloc;
  if (r0 < split1)      { W = W0; rloc = r0; }
  else if (r0 < split2) { W = W1; rloc = r0 - split1; }
  else                  { W = W2; rloc = r0 - split2; }

  const int lm = l & 15;                  // M / N index within 16-tile
  const int lk = l >> 4;                  // k-group 0..3 (8 k each)

  const float* wp0 = W + (size_t)(rloc + lm) * HID_ + k0 + lk * 8;
  const float* wp1 = wp0 + (size_t)16 * HID_;
  const unsigned short* bh = XBhi + ((size_t)(k0 / 8 + lk) * 64 + lm) * 8;
  const unsigned short* bl = XBlo + ((size_t)(k0 / 8 + lk) * 64 + lm) * 8;

  f32x4 acc[2][4];
  #pragma unroll
  for (int rt = 0; rt < 2; ++rt)
    #pragma unroll
    for (int ct = 0; ct < 4; ++ct)
      #pragma unroll
      for (int i = 0; i < 4; ++i) acc[rt][ct][i] = 0.f;

  #pragma unroll
  for (int ks = 0; ks < NSTEP; ++ks) {
    bf16x8 Bh[4], Bl[4];
    #pragma unroll
    for (int ct = 0; ct < 4; ++ct) {
      Bh[ct] = *(const bf16x8*)(bh + (size_t)ks * 2048 + ct * 128);
      Bl[ct] = *(const bf16x8*)(bl + (size_t)ks * 2048 + ct * 128);
    }
    #pragma unroll
    for (int rt = 0; rt < 2; ++rt) {
      const float* wp = (rt ? wp1 : wp0) + ks * 32;
      float4 a0 = *(const float4*)wp;
      float4 a1 = *(const float4*)(wp + 4);
      float xs[8] = {a0.x, a0.y, a0.z, a0.w, a1.x, a1.y, a1.z, a1.w};
      bf16x8 Ah, Al;
      #pragma unroll
      for (int j = 0; j < 8; ++j) {
        unsigned short h = f2bf(xs[j]);
        Ah[j] = (short)h;
        Al[j] = (short)f2bf(xs[j] - bf2f(h));
      }
      #pragma unroll
      for (int ct = 0; ct < 4; ++ct) {
        acc[rt][ct] = __builtin_amdgcn_mfma_f32_16x16x32_bf16(Ah, Bh[ct], acc[rt][ct], 0, 0, 0);
        acc[rt][ct] = __builtin_amdgcn_mfma_f32_16x16x32_bf16(Al, Bh[ct], acc[rt][ct], 0, 0, 0);
        acc[rt][ct] = __builtin_amdgcn_mfma_f32_16x16x32_bf16(Ah, Bl[ct], acc[rt][ct], 0, 0, 0);
      }
    }
  }

  // C layout: col = lane&15, row = (lane>>4)*4 + reg
  #pragma unroll
  for (int rt = 0; rt < 2; ++rt)
    #pragma unroll
    for (int ct = 0; ct < 4; ++ct) {
      int row = r0 + rt * 16 + lk * 4;
      int bat = ct * 16 + lm;
      #pragma unroll
      for (int i = 0; i < 4; ++i)
        part[((size_t)blockIdx.y * rows_total + row + i) * 64 + bat] = acc[rt][ct][i];
    }
}

// ---------------------------------------------------------------------------
// Sum K-split partials + RoPE (half-split). q scaled by 1/sqrt(D).
// qkvf layout: q[64][32][128] | k[64][8][128] | v[64][8][128]
// ---------------------------------------------------------------------------
__global__ __launch_bounds__(256) void reduce_rope(
    const float* __restrict__ part, const float* __restrict__ cosT,
    const float* __restrict__ sinT, const int* __restrict__ positions,
    float* __restrict__ qkvf)
{
  const int bb  = threadIdx.x & 63;
  const int cid = blockIdx.x * 4 + (threadIdx.x >> 6);  // 0..3071
  const int pos = positions[bb];

  if (cid < 2048) {                       // q pairs: (hq, d0)
    const int hq = cid >> 6, d0 = cid & 63;
    const int r1 = hq * 128 + d0;
    float x1 = 0.f, x2 = 0.f;
    #pragma unroll 8
    for (int ks = 0; ks < KS1; ++ks) {
      x1 += part[((size_t)ks * QKV_ROWS + r1) * 64 + bb];
      x2 += part[((size_t)ks * QKV_ROWS + r1 + 64) * 64 + bb];
    }
    float c = cosT[pos * 64 + d0], s = sinT[pos * 64 + d0];
    const float scale = 0.08838834764831843f;   // 1/sqrt(128)
    qkvf[(size_t)(bb * 32 + hq) * 128 + d0]      = (x1 * c - x2 * s) * scale;
    qkvf[(size_t)(bb * 32 + hq) * 128 + d0 + 64] = (x2 * c + x1 * s) * scale;
  } else if (cid < 2560) {                // k pairs
    const int c2 = cid - 2048;
    const int kh = c2 >> 6, d0 = c2 & 63;
    const int r1 = 4096 + kh * 128 + d0;
    float x1 = 0.f, x2 = 0.f;
    #pragma unroll 8
    for (int ks = 0; ks < KS1; ++ks) {
      x1 += part[((size_t)ks * QKV_ROWS + r1) * 64 + bb];
      x2 += part[((size_t)ks * QKV_ROWS + r1 + 64) * 64 + bb];
    }
    float c = cosT[pos * 64 + d0], s = sinT[pos * 64 + d0];
    qkvf[262144 + (size_t)(bb * 8 + kh) * 128 + d0]      = x1 * c - x2 * s;
    qkvf[262144 + (size_t)(bb * 8 + kh) * 128 + d0 + 64] = x2 * c + x1 * s;
  } else {                                // v passthrough
    const int c2 = cid - 2560;
    const int kh = c2 >> 6, d0 = c2 & 63;
    const int r1 = 5120 + kh * 128 + d0;
    float x1 = 0.f, x2 = 0.f;
    #pragma unroll 8
    for (int ks = 0; ks < KS1; ++ks) {
      x1 += part[((size_t)ks * QKV_ROWS + r1) * 64 + bb];
      x2 += part[((size_t)ks * QKV_ROWS + r1 + 64) * 64 + bb];
    }
    qkvf[327680 + (size_t)(bb * 8 + kh) * 128 + d0]      = x1;
    qkvf[327680 + (size_t)(bb * 8 + kh) * 128 + d0 + 64] = x2;
  }
}

// ---------------------------------------------------------------------------
// Flash-decode split attention. LDS cut 33->10 KB (in-wave half-pair
// reduction via shfl_xor(32)) -> 8 blocks/CU, full occupancy.
// ---------------------------------------------------------------------------
__global__ __launch_bounds__(256, 8) void attn_split(
    const float* __restrict__ qkvf, const float* __restrict__ kcache,
    const float* __restrict__ vcache, const int* __restrict__ btab,
    const int* __restrict__ ctxlen,
    float* __restrict__ part_o,   // [B*HKV*SPLITS][4][128]
    float* __restrict__ part_ml)  // [B*HKV*SPLITS][4][2]
{
  const int bid = blockIdx.x;
  const int s   = bid & (SPLITS - 1);
  const int bh  = bid >> 3;
  const int b = bh >> 3, h = bh & 7;
  const int ctx   = ctxlen[b];
  const int chunk = (ctx + SPLITS - 1) / SPLITS;   // <= 128
  const int t0 = s * chunk;
  const int t1 = min(ctx, t0 + chunk);
  const int n  = t1 - t0;
  const int last = ctx - 1;

  const int tid  = threadIdx.x;
  const int half = tid >> 5;     // 0..7
  const int d4   = tid & 31;

  __shared__ float sc[4][128];
  __shared__ float wred[4][4][128];   // [wave][g][d]
  __shared__ float red[4][2];         // m, l per group-head

  float4 qf[4];
  #pragma unroll
  for (int g = 0; g < 4; ++g)
    qf[g] = *(const float4*)(qkvf + (size_t)(b * 32 + h * 4 + g) * 128 + d4 * 4);

  const float* knew = qkvf + 262144 + (size_t)(b * 8 + h) * 128;
  const float* vnew = qkvf + 327680 + (size_t)(b * 8 + h) * 128;

  // ---- pass 1: scores
  for (int t = t0 + half; t < t1; t += 8) {
    const float* kp;
    if (t == last) kp = knew;
    else {
      int slot = btab[b * MAXB_ + (t >> 4)] * BS_ + (t & 15);
      kp = kcache + ((size_t)slot * HKV_ + h) * D_;
    }
    float4 kv = *(const float4*)(kp + d4 * 4);
    float p0 = qf[0].x * kv.x + qf[0].y * kv.y + qf[0].z * kv.z + qf[0].w * kv.w;
    float p1 = qf[1].x * kv.x + qf[1].y * kv.y + qf[1].z * kv.z + qf[1].w * kv.w;
    float p2 = qf[2].x * kv.x + qf[2].y * kv.y + qf[2].z * kv.z + qf[2].w * kv.w;
    float p3 = qf[3].x * kv.x + qf[3].y * kv.y + qf[3].z * kv.z + qf[3].w * kv.w;
    #pragma unroll
    for (int m = 16; m >= 1; m >>= 1) {
      p0 += __shfl_xor(p0, m);
      p1 += __shfl_xor(p1, m);
      p2 += __shfl_xor(p2, m);
      p3 += __shfl_xor(p3, m);
    }
    if (d4 == 0) {
      int i = t - t0;
      sc[0][i] = p0; sc[1][i] = p1; sc[2][i] = p2; sc[3][i] = p3;
    }
  }
  __syncthreads();

  // ---- partial softmax: wave w handles group-head g = w
  {
    const int w = tid >> 6, l = tid & 63;
    float mx = -1e30f;
    for (int i = l; i < n; i += 64) mx = fmaxf(mx, sc[w][i]);
    #pragma unroll
    for (int m = 32; m >= 1; m >>= 1) mx = fmaxf(mx, __shfl_xor(mx, m));
    float lsum = 0.f;
    for (int i = l; i < n; i += 64) {
      float p = __expf(sc[w][i] - mx);
      sc[w][i] = p;
      lsum += p;
    }
    #pragma unroll
    for (int m = 32; m >= 1; m >>= 1) lsum += __shfl_xor(lsum, m);
    if (l == 0) { red[w][0] = mx; red[w][1] = lsum; }
  }
  __syncthreads();

  // ---- pass 2: sum p*V (unnormalized)
  float acc[4][4] = {{0.f}};
  for (int t = t0 + half; t < t1; t += 8) {
    const float* vp;
    if (t == last) vp = vnew;
    else {
      int slot = btab[b * MAXB_ + (t >> 4)] * BS_ + (t & 15);
      vp = vcache + ((size_t)slot * HKV_ + h) * D_;
    }
    float4 vv = *(const float4*)(vp + d4 * 4);
    int i = t - t0;
    #pragma unroll
    for (int g = 0; g < 4; ++g) {
      float p = sc[g][i];
      acc[g][0] += p * vv.x; acc[g][1] += p * vv.y;
      acc[g][2] += p * vv.z; acc[g][3] += p * vv.w;
    }
  }
  // reduce half-pair within wave (lane l <-> l^32 share d4)
  #pragma unroll
  for (int g = 0; g < 4; ++g)
    #pragma unroll
    for (int j = 0; j < 4; ++j)
      acc[g][j] += __shfl_xor(acc[g][j], 32);
  if ((tid & 32) == 0) {
    int wv = tid >> 6;
    #pragma unroll
    for (int g = 0; g < 4; ++g)
      #pragma unroll
      for (int j = 0; j < 4; ++j)
        wred[wv][g][d4 * 4 + j] = acc[g][j];
  }
  __syncthreads();

  for (int idx = tid; idx < 512; idx += 256) {
    int g = idx >> 7, d = idx & 127;
    float v = wred[0][g][d] + wred[1][g][d] + wred[2][g][d] + wred[3][g][d];
    part_o[(size_t)bid * 512 + idx] = v;
  }
  if (tid < 8) part_ml[(size_t)bid * 8 + tid] = red[tid >> 1][tid & 1];
}

// ---------------------------------------------------------------------------
// Combine split partials AND emit bf16 hi/lo XB layout for the O-GEMM:
// val = sum_s exp(m_s-M) o_s / sum_s exp(m_s-M) l_s ; XB[kg][b][j].
// ---------------------------------------------------------------------------
__global__ __launch_bounds__(256) void attn_combine_xb(
    const float* __restrict__ part_o, const float* __restrict__ part_ml,
    unsigned short* __restrict__ XBhi, unsigned short* __restrict__ XBlo)
{
  const int bh = blockIdx.x;            // 0..511
  const int b = bh >> 3, h = bh & 7;
  const int tid = threadIdx.x;

  __shared__ float Sg[SPLITS][4];
  __shared__ float Dg[4];

  if (tid < 32) {                       // lane = s*4+g
    int s = tid >> 2, g = tid & 3;
    float m = part_ml[((size_t)bh * SPLITS + s) * 8 + g * 2];
    float l = part_ml[((size_t)bh * SPLITS + s) * 8 + g * 2 + 1];
    float M = m;
    #pragma unroll
    for (int k = 4; k <= 16; k <<= 1) M = fmaxf(M, __shfl_xor(M, k));
    float scl = __expf(m - M);
    float dl = l * scl;
    #pragma unroll
    for (int k = 4; k <= 16; k <<= 1) dl += __shfl_xor(dl, k);
    Sg[s][g] = scl;
    if (s == 0) Dg[g] = dl;
  }
  __syncthreads();

  for (int idx = tid; idx < 512; idx += 256) {
    int g = idx >> 7, d = idx & 127;
    float num = 0.f;
    #pragma unroll
    for (int s = 0; s < SPLITS; ++s)
      num += Sg[s][g] * part_o[((size_t)bh * SPLITS + s) * 512 + idx];
    float val = num / Dg[g];
    int col = (h * 4 + g) * 128 + d;    // column in attn-output row b
    int kg = col >> 3, j = col & 7;
    unsigned short hi = f2bf(val);
    unsigned short lo = f2bf(val - bf2f(hi));
    XBhi[((size_t)kg * 64 + b) * 8 + j] = hi;
    XBlo[((size_t)kg * 64 + b) * 8 + j] = lo;
  }
}

// ---------------------------------------------------------------------------
// Sum K-split partials of O-GEMM ([ks][row][batch]) -> out[b][row] via LDS
// transpose, coalesced both sides.
// ---------------------------------------------------------------------------
__global__ __launch_bounds__(256) void reduce_out_t(
    const float* __restrict__ part, float* __restrict__ out)
{
  __shared__ float t[64][65];
  const int i0 = blockIdx.x * 64;
  const int lane = threadIdx.x & 63, q = threadIdx.x >> 6;

  #pragma unroll
  for (int rr = q; rr < 64; rr += 4) {
    float s = 0.f;
    #pragma unroll 8
    for (int ks = 0; ks < KS1; ++ks)
      s += part[((size_t)ks * O_ROWS + i0 + rr) * 64 + lane];
    t[rr][lane] = s;
  }
  __syncthreads();
  #pragma unroll
  for (int rr = q; rr < 64; rr += 4)
    out[(size_t)rr * O_ROWS + i0 + lane] = t[lane][rr];
}

// ---------------------------------------------------------------------------
extern "C" void kernel_launch(void* const* d_in, const int* in_sizes, int n_in,
                              void* d_out, int out_size, void* d_ws, size_t ws_size,
                              hipStream_t stream)
{
  (void)in_sizes; (void)n_in; (void)out_size; (void)ws_size;
  const float* hidden    = (const float*)d_in[0];
  const int*   positions = (const int*)d_in[1];
  const float* cosT      = (const float*)d_in[2];
  const float* sinT      = (const float*)d_in[3];
  const float* kcache    = (const float*)d_in[4];
  const float* vcache    = (const float*)d_in[5];
  const int*   btab      = (const int*)d_in[7];
  const int*   ctx       = (const int*)d_in[8];
  const float* Wq        = (const float*)d_in[9];
  const float* Wk        = (const float*)d_in[10];
  const float* Wv        = (const float*)d_in[11];
  const float* Wo        = (const float*)d_in[12];
  float* out = (float*)d_out;

  float* ws      = (float*)d_ws;
  float* region  = ws;                       // reused 3x
  float* qkvf    = region + REGION_SZ;
  unsigned short* XBhi = (unsigned short*)(qkvf + QKVF_SZ);
  unsigned short* XBlo = XBhi + XB_SZ;
  // phase 1
  float* part1   = region;
  // phase 2 (after reduce_rope, part1 dead)
  float* part_o  = region;                                     // 4096*512
  float* part_ml = region + (size_t)B_ * HKV_ * SPLITS * 512;  // 4096*8
  // phase 3 (after attn_combine_xb, part_o dead)
  float* part3   = region;

  convert_x<<<128, 256, 0, stream>>>(hidden, XBhi, XBlo);
  gemm_mfma<<<dim3(QKV_ROWS / 128, KS1), 256, 0, stream>>>(
      Wq, Wk, Wv, XBhi, XBlo, 4096, 5120, QKV_ROWS, part1);
  reduce_rope<<<768, 256, 0, stream>>>(part1, cosT, sinT, positions, qkvf);
  attn_split<<<B_ * HKV_ * SPLITS, 256, 0, stream>>>(
      qkvf, kcache, vcache, btab, ctx, part_o, part_ml);
  attn_combine_xb<<<B_ * HKV_, 256, 0, stream>>>(part_o, part_ml, XBhi, XBlo);
  gemm_mfma<<<dim3(O_ROWS / 128, KS1), 256, 0, stream>>>(
      Wo, Wo, Wo, XBhi, XBlo, O_ROWS, O_ROWS, O_ROWS, part3);
  reduce_out_t<<<O_ROWS / 64, 256, 0, stream>>>(part3, out);
}

// Round 11
// 213.219 us; speedup vs baseline: 1.0510x; 1.0510x over previous
//
#include <hip/hip_runtime.h>

#define B_    64
#define HID_  4096
#define HQ_   32
#define HKV_  8
#define D_    128
#define BS_   16
#define MAXB_ 64

#define KSQ     16                // K-split, QKV GEMM (chunk 256, 8 steps)
#define KSO     32                // K-split, O GEMM   (chunk 128, 4 steps)
#define QKV_ROWS 6144
#define O_ROWS   4096
#define SPLITS  8

#define REGION_SZ ((size_t)KSO * O_ROWS * 64)     // 8.4M floats (max overlay)
#define QKVF_SZ  ((size_t)64 * 6144)
#define XB_SZ    ((size_t)HID_ * 64)

typedef __attribute__((ext_vector_type(8))) short bf16x8;
typedef __attribute__((ext_vector_type(4))) float f32x4;

__device__ inline unsigned short f2bf(float x) {
  union { float f; unsigned u; } v; v.f = x;
  unsigned r = v.u + 0x7fff + ((v.u >> 16) & 1);   // RNE
  return (unsigned short)(r >> 16);
}
__device__ inline float bf2f(unsigned short h) {
  union { float f; unsigned u; } v; v.u = ((unsigned)h) << 16; return v.f;
}

// ---------------------------------------------------------------------------
// Convert X [64][HID] fp32 -> fragment-contiguous bf16 hi/lo:
// XB[kg][b][j] = bf16(X[b][kg*8+j])
// ---------------------------------------------------------------------------
__global__ __launch_bounds__(256) void convert_x(
    const float* __restrict__ X, unsigned short* __restrict__ XBhi,
    unsigned short* __restrict__ XBlo)
{
  int idx = blockIdx.x * 256 + threadIdx.x;   // 0..32767
  int kg = idx >> 6, b = idx & 63;
  const float* xp = X + (size_t)b * HID_ + kg * 8;
  float4 a = *(const float4*)xp, c = *(const float4*)(xp + 4);
  float xs[8] = {a.x, a.y, a.z, a.w, c.x, c.y, c.z, c.w};
  unsigned short hi[8], lo[8];
  #pragma unroll
  for (int j = 0; j < 8; ++j) {
    hi[j] = f2bf(xs[j]);
    lo[j] = f2bf(xs[j] - bf2f(hi[j]));
  }
  *(uint4*)(XBhi + (size_t)idx * 8) = *(const uint4*)hi;
  *(uint4*)(XBlo + (size_t)idx * 8) = *(const uint4*)lo;
}

// ---------------------------------------------------------------------------
// Split-bf16 MFMA skinny GEMM partial with async LDS-DMA A-staging.
// Block: 128 rows x 64 batches; wave w owns rows [w*32, w*32+32).
// A-tile [128 rows][32 k] fp32 = 16KB staged per K-step via
// global_load_lds width=16, double-buffered: ISSUE(s+1) overlaps compute(s).
// Source granule pre-swizzled (g ^= row&7); same XOR on ds_read -> no bank
// conflicts. B (XB hi/lo, L2-resident) read direct to regs.
// 3 MFMA terms: hi*hi + lo*hi + hi*lo. part[ks][row][64batch].
// ---------------------------------------------------------------------------
__global__ __launch_bounds__(256, 3) void gemm_mfma(
    const float* __restrict__ W0, const float* __restrict__ W1,
    const float* __restrict__ W2,
    const unsigned short* __restrict__ XBhi,
    const unsigned short* __restrict__ XBlo,
    int split1, int split2, int rows_total, int kchunk, int nstep,
    float* __restrict__ part)
{
  __shared__ float Abuf[2][128 * 32];   // 2 x 16KB

  const int tid = threadIdx.x;
  const int l   = tid & 63;
  const int w   = tid >> 6;             // wave 0..3
  const int r0  = blockIdx.x * 128;
  const int k0  = blockIdx.y * kchunk;

  const float* W; int rloc;
  if (r0 < split1)      { W = W0; rloc = r0; }
  else if (r0 < split2) { W = W1; rloc = r0 - split1; }
  else                  { W = W2; rloc = r0 - split2; }

  const int lm = l & 15;                // M(row)/N(batch) index in 16-tile
  const int lk = l >> 4;                // k-group 0..3

  const float* Wb = W + (size_t)rloc * HID_ + k0;
  const unsigned short* bh = XBhi + ((size_t)(k0 / 8 + lk) * 64 + lm) * 8;
  const unsigned short* bl = XBlo + ((size_t)(k0 / 8 + lk) * 64 + lm) * 8;

  // staging slot idx = c*256+tid; row=idx>>3, cg=idx&7 holds global granule
  // g = cg ^ (row&7). LDS dest base is wave-uniform (tid&~63).
  const int sidx0 = tid;
  const int wbase = tid & ~63;

  #define ISSUE(buf, step)                                                   \
    {                                                                        \
      const float* Wk = Wb + (size_t)(step) * 32;                            \
      _Pragma("unroll")                                                      \
      for (int c = 0; c < 4; ++c) {                                          \
        int idx = c * 256 + sidx0;                                           \
        int row = idx >> 3, cg = idx & 7;                                    \
        int g = cg ^ (row & 7);                                              \
        const float* gsrc = Wk + (size_t)row * HID_ + g * 4;                 \
        float* ldst = &Abuf[buf][(size_t)(c * 256 + wbase) * 4];             \
        __builtin_amdgcn_global_load_lds(                                    \
            (const __attribute__((address_space(1))) unsigned int*)gsrc,     \
            (__attribute__((address_space(3))) unsigned int*)ldst, 16, 0, 0);\
      }                                                                      \
    }

  f32x4 acc[2][4];
  #pragma unroll
  for (int rt = 0; rt < 2; ++rt)
    #pragma unroll
    for (int ct = 0; ct < 4; ++ct)
      #pragma unroll
      for (int i = 0; i < 4; ++i) acc[rt][ct][i] = 0.f;

  ISSUE(0, 0);

  for (int s = 0; s < nstep; ++s) {
    __syncthreads();                       // drains DMA -> buf[s&1] ready
    if (s + 1 < nstep) ISSUE((s + 1) & 1, s + 1);   // overlaps compute

    bf16x8 Bh[4], Bl[4];
    #pragma unroll
    for (int ct = 0; ct < 4; ++ct) {
      Bh[ct] = *(const bf16x8*)(bh + (size_t)s * 2048 + ct * 128);
      Bl[ct] = *(const bf16x8*)(bl + (size_t)s * 2048 + ct * 128);
    }

    const float* A = Abuf[s & 1];
    #pragma unroll
    for (int rt = 0; rt < 2; ++rt) {
      int r = w * 32 + rt * 16 + lm;
      const float* base = A + r * 32;
      int g0 = (2 * lk) ^ (r & 7);
      int g1 = (2 * lk + 1) ^ (r & 7);
      float4 a0 = *(const float4*)(base + g0 * 4);   // k = lk*8 .. +3
      float4 a1 = *(const float4*)(base + g1 * 4);   // k = lk*8+4 .. +7
      float xs[8] = {a0.x, a0.y, a0.z, a0.w, a1.x, a1.y, a1.z, a1.w};
      bf16x8 Ah, Al;
      #pragma unroll
      for (int j = 0; j < 8; ++j) {
        unsigned short h = f2bf(xs[j]);
        Ah[j] = (short)h;
        Al[j] = (short)f2bf(xs[j] - bf2f(h));
      }
      #pragma unroll
      for (int ct = 0; ct < 4; ++ct) {
        acc[rt][ct] = __builtin_amdgcn_mfma_f32_16x16x32_bf16(Ah, Bh[ct], acc[rt][ct], 0, 0, 0);
        acc[rt][ct] = __builtin_amdgcn_mfma_f32_16x16x32_bf16(Al, Bh[ct], acc[rt][ct], 0, 0, 0);
        acc[rt][ct] = __builtin_amdgcn_mfma_f32_16x16x32_bf16(Ah, Bl[ct], acc[rt][ct], 0, 0, 0);
      }
    }
  }
  #undef ISSUE

  // C layout: col = lane&15 (batch), row = (lane>>4)*4 + reg
  #pragma unroll
  for (int rt = 0; rt < 2; ++rt)
    #pragma unroll
    for (int ct = 0; ct < 4; ++ct) {
      int row = r0 + w * 32 + rt * 16 + lk * 4;
      int bat = ct * 16 + lm;
      #pragma unroll
      for (int i = 0; i < 4; ++i)
        part[((size_t)blockIdx.y * rows_total + row + i) * 64 + bat] = acc[rt][ct][i];
    }
}

// ---------------------------------------------------------------------------
// Sum K-split partials + RoPE (half-split). q scaled by 1/sqrt(D).
// qkvf layout: q[64][32][128] | k[64][8][128] | v[64][8][128]
// ---------------------------------------------------------------------------
__global__ __launch_bounds__(256) void reduce_rope(
    const float* __restrict__ part, const float* __restrict__ cosT,
    const float* __restrict__ sinT, const int* __restrict__ positions,
    float* __restrict__ qkvf)
{
  const int bb  = threadIdx.x & 63;
  const int cid = blockIdx.x * 4 + (threadIdx.x >> 6);  // 0..3071
  const int pos = positions[bb];

  if (cid < 2048) {                       // q pairs: (hq, d0)
    const int hq = cid >> 6, d0 = cid & 63;
    const int r1 = hq * 128 + d0;
    float x1 = 0.f, x2 = 0.f;
    #pragma unroll 8
    for (int ks = 0; ks < KSQ; ++ks) {
      x1 += part[((size_t)ks * QKV_ROWS + r1) * 64 + bb];
      x2 += part[((size_t)ks * QKV_ROWS + r1 + 64) * 64 + bb];
    }
    float c = cosT[pos * 64 + d0], s = sinT[pos * 64 + d0];
    const float scale = 0.08838834764831843f;   // 1/sqrt(128)
    qkvf[(size_t)(bb * 32 + hq) * 128 + d0]      = (x1 * c - x2 * s) * scale;
    qkvf[(size_t)(bb * 32 + hq) * 128 + d0 + 64] = (x2 * c + x1 * s) * scale;
  } else if (cid < 2560) {                // k pairs
    const int c2 = cid - 2048;
    const int kh = c2 >> 6, d0 = c2 & 63;
    const int r1 = 4096 + kh * 128 + d0;
    float x1 = 0.f, x2 = 0.f;
    #pragma unroll 8
    for (int ks = 0; ks < KSQ; ++ks) {
      x1 += part[((size_t)ks * QKV_ROWS + r1) * 64 + bb];
      x2 += part[((size_t)ks * QKV_ROWS + r1 + 64) * 64 + bb];
    }
    float c = cosT[pos * 64 + d0], s = sinT[pos * 64 + d0];
    qkvf[262144 + (size_t)(bb * 8 + kh) * 128 + d0]      = x1 * c - x2 * s;
    qkvf[262144 + (size_t)(bb * 8 + kh) * 128 + d0 + 64] = x2 * c + x1 * s;
  } else {                                // v passthrough
    const int c2 = cid - 2560;
    const int kh = c2 >> 6, d0 = c2 & 63;
    const int r1 = 5120 + kh * 128 + d0;
    float x1 = 0.f, x2 = 0.f;
    #pragma unroll 8
    for (int ks = 0; ks < KSQ; ++ks) {
      x1 += part[((size_t)ks * QKV_ROWS + r1) * 64 + bb];
      x2 += part[((size_t)ks * QKV_ROWS + r1 + 64) * 64 + bb];
    }
    qkvf[327680 + (size_t)(bb * 8 + kh) * 128 + d0]      = x1;
    qkvf[327680 + (size_t)(bb * 8 + kh) * 128 + d0 + 64] = x2;
  }
}

// ---------------------------------------------------------------------------
// Flash-decode split attention (r10 version: 10KB LDS, 8 blocks/CU).
// ---------------------------------------------------------------------------
__global__ __launch_bounds__(256, 8) void attn_split(
    const float* __restrict__ qkvf, const float* __restrict__ kcache,
    const float* __restrict__ vcache, const int* __restrict__ btab,
    const int* __restrict__ ctxlen,
    float* __restrict__ part_o,   // [B*HKV*SPLITS][4][128]
    float* __restrict__ part_ml)  // [B*HKV*SPLITS][4][2]
{
  const int bid = blockIdx.x;
  const int s   = bid & (SPLITS - 1);
  const int bh  = bid >> 3;
  const int b = bh >> 3, h = bh & 7;
  const int ctx   = ctxlen[b];
  const int chunk = (ctx + SPLITS - 1) / SPLITS;   // <= 128
  const int t0 = s * chunk;
  const int t1 = min(ctx, t0 + chunk);
  const int n  = t1 - t0;
  const int last = ctx - 1;

  const int tid  = threadIdx.x;
  const int half = tid >> 5;
  const int d4   = tid & 31;

  __shared__ float sc[4][128];
  __shared__ float wred[4][4][128];
  __shared__ float red[4][2];

  float4 qf[4];
  #pragma unroll
  for (int g = 0; g < 4; ++g)
    qf[g] = *(const float4*)(qkvf + (size_t)(b * 32 + h * 4 + g) * 128 + d4 * 4);

  const float* knew = qkvf + 262144 + (size_t)(b * 8 + h) * 128;
  const float* vnew = qkvf + 327680 + (size_t)(b * 8 + h) * 128;

  for (int t = t0 + half; t < t1; t += 8) {
    const float* kp;
    if (t == last) kp = knew;
    else {
      int slot = btab[b * MAXB_ + (t >> 4)] * BS_ + (t & 15);
      kp = kcache + ((size_t)slot * HKV_ + h) * D_;
    }
    float4 kv = *(const float4*)(kp + d4 * 4);
    float p0 = qf[0].x * kv.x + qf[0].y * kv.y + qf[0].z * kv.z + qf[0].w * kv.w;
    float p1 = qf[1].x * kv.x + qf[1].y * kv.y + qf[1].z * kv.z + qf[1].w * kv.w;
    float p2 = qf[2].x * kv.x + qf[2].y * kv.y + qf[2].z * kv.z + qf[2].w * kv.w;
    float p3 = qf[3].x * kv.x + qf[3].y * kv.y + qf[3].z * kv.z + qf[3].w * kv.w;
    #pragma unroll
    for (int m = 16; m >= 1; m >>= 1) {
      p0 += __shfl_xor(p0, m);
      p1 += __shfl_xor(p1, m);
      p2 += __shfl_xor(p2, m);
      p3 += __shfl_xor(p3, m);
    }
    if (d4 == 0) {
      int i = t - t0;
      sc[0][i] = p0; sc[1][i] = p1; sc[2][i] = p2; sc[3][i] = p3;
    }
  }
  __syncthreads();

  {
    const int w = tid >> 6, l = tid & 63;
    float mx = -1e30f;
    for (int i = l; i < n; i += 64) mx = fmaxf(mx, sc[w][i]);
    #pragma unroll
    for (int m = 32; m >= 1; m >>= 1) mx = fmaxf(mx, __shfl_xor(mx, m));
    float lsum = 0.f;
    for (int i = l; i < n; i += 64) {
      float p = __expf(sc[w][i] - mx);
      sc[w][i] = p;
      lsum += p;
    }
    #pragma unroll
    for (int m = 32; m >= 1; m >>= 1) lsum += __shfl_xor(lsum, m);
    if (l == 0) { red[w][0] = mx; red[w][1] = lsum; }
  }
  __syncthreads();

  float acc[4][4] = {{0.f}};
  for (int t = t0 + half; t < t1; t += 8) {
    const float* vp;
    if (t == last) vp = vnew;
    else {
      int slot = btab[b * MAXB_ + (t >> 4)] * BS_ + (t & 15);
      vp = vcache + ((size_t)slot * HKV_ + h) * D_;
    }
    float4 vv = *(const float4*)(vp + d4 * 4);
    int i = t - t0;
    #pragma unroll
    for (int g = 0; g < 4; ++g) {
      float p = sc[g][i];
      acc[g][0] += p * vv.x; acc[g][1] += p * vv.y;
      acc[g][2] += p * vv.z; acc[g][3] += p * vv.w;
    }
  }
  #pragma unroll
  for (int g = 0; g < 4; ++g)
    #pragma unroll
    for (int j = 0; j < 4; ++j)
      acc[g][j] += __shfl_xor(acc[g][j], 32);
  if ((tid & 32) == 0) {
    int wv = tid >> 6;
    #pragma unroll
    for (int g = 0; g < 4; ++g)
      #pragma unroll
      for (int j = 0; j < 4; ++j)
        wred[wv][g][d4 * 4 + j] = acc[g][j];
  }
  __syncthreads();

  for (int idx = tid; idx < 512; idx += 256) {
    int g = idx >> 7, d = idx & 127;
    float v = wred[0][g][d] + wred[1][g][d] + wred[2][g][d] + wred[3][g][d];
    part_o[(size_t)bid * 512 + idx] = v;
  }
  if (tid < 8) part_ml[(size_t)bid * 8 + tid] = red[tid >> 1][tid & 1];
}

// ---------------------------------------------------------------------------
// Combine split partials AND emit bf16 hi/lo XB layout for the O-GEMM.
// ---------------------------------------------------------------------------
__global__ __launch_bounds__(256) void attn_combine_xb(
    const float* __restrict__ part_o, const float* __restrict__ part_ml,
    unsigned short* __restrict__ XBhi, unsigned short* __restrict__ XBlo)
{
  const int bh = blockIdx.x;            // 0..511
  const int b = bh >> 3, h = bh & 7;
  const int tid = threadIdx.x;

  __shared__ float Sg[SPLITS][4];
  __shared__ float Dg[4];

  if (tid < 32) {
    int s = tid >> 2, g = tid & 3;
    float m = part_ml[((size_t)bh * SPLITS + s) * 8 + g * 2];
    float l = part_ml[((size_t)bh * SPLITS + s) * 8 + g * 2 + 1];
    float M = m;
    #pragma unroll
    for (int k = 4; k <= 16; k <<= 1) M = fmaxf(M, __shfl_xor(M, k));
    float scl = __expf(m - M);
    float dl = l * scl;
    #pragma unroll
    for (int k = 4; k <= 16; k <<= 1) dl += __shfl_xor(dl, k);
    Sg[s][g] = scl;
    if (s == 0) Dg[g] = dl;
  }
  __syncthreads();

  for (int idx = tid; idx < 512; idx += 256) {
    int g = idx >> 7, d = idx & 127;
    float num = 0.f;
    #pragma unroll
    for (int s = 0; s < SPLITS; ++s)
      num += Sg[s][g] * part_o[((size_t)bh * SPLITS + s) * 512 + idx];
    float val = num / Dg[g];
    int col = (h * 4 + g) * 128 + d;
    int kg = col >> 3, j = col & 7;
    unsigned short hi = f2bf(val);
    unsigned short lo = f2bf(val - bf2f(hi));
    XBhi[((size_t)kg * 64 + b) * 8 + j] = hi;
    XBlo[((size_t)kg * 64 + b) * 8 + j] = lo;
  }
}

// ---------------------------------------------------------------------------
// Sum KSO partials of O-GEMM ([ks][row][batch]) -> out[b][row] via LDS
// transpose, coalesced both sides.
// ---------------------------------------------------------------------------
__global__ __launch_bounds__(256) void reduce_out_t(
    const float* __restrict__ part, float* __restrict__ out)
{
  __shared__ float t[64][65];
  const int i0 = blockIdx.x * 64;
  const int lane = threadIdx.x & 63, q = threadIdx.x >> 6;

  #pragma unroll
  for (int rr = q; rr < 64; rr += 4) {
    float s = 0.f;
    #pragma unroll 8
    for (int ks = 0; ks < KSO; ++ks)
      s += part[((size_t)ks * O_ROWS + i0 + rr) * 64 + lane];
    t[rr][lane] = s;
  }
  __syncthreads();
  #pragma unroll
  for (int rr = q; rr < 64; rr += 4)
    out[(size_t)rr * O_ROWS + i0 + lane] = t[lane][rr];
}

// ---------------------------------------------------------------------------
extern "C" void kernel_launch(void* const* d_in, const int* in_sizes, int n_in,
                              void* d_out, int out_size, void* d_ws, size_t ws_size,
                              hipStream_t stream)
{
  (void)in_sizes; (void)n_in; (void)out_size; (void)ws_size;
  const float* hidden    = (const float*)d_in[0];
  const int*   positions = (const int*)d_in[1];
  const float* cosT      = (const float*)d_in[2];
  const float* sinT      = (const float*)d_in[3];
  const float* kcache    = (const float*)d_in[4];
  const float* vcache    = (const float*)d_in[5];
  const int*   btab      = (const int*)d_in[7];
  const int*   ctx       = (const int*)d_in[8];
  const float* Wq        = (const float*)d_in[9];
  const float* Wk        = (const float*)d_in[10];
  const float* Wv        = (const float*)d_in[11];
  const float* Wo        = (const float*)d_in[12];
  float* out = (float*)d_out;

  float* ws      = (float*)d_ws;
  float* region  = ws;                       // reused 3x
  float* qkvf    = region + REGION_SZ;
  unsigned short* XBhi = (unsigned short*)(qkvf + QKVF_SZ);
  unsigned short* XBlo = XBhi + XB_SZ;
  float* part1   = region;                                     // phase 1
  float* part_o  = region;                                     // phase 2
  float* part_ml = region + (size_t)B_ * HKV_ * SPLITS * 512;
  float* part3   = region;                                     // phase 3

  convert_x<<<128, 256, 0, stream>>>(hidden, XBhi, XBlo);
  gemm_mfma<<<dim3(QKV_ROWS / 128, KSQ), 256, 0, stream>>>(
      Wq, Wk, Wv, XBhi, XBlo, 4096, 5120, QKV_ROWS, HID_ / KSQ, HID_ / KSQ / 32, part1);
  reduce_rope<<<768, 256, 0, stream>>>(part1, cosT, sinT, positions, qkvf);
  attn_split<<<B_ * HKV_ * SPLITS, 256, 0, stream>>>(
      qkvf, kcache, vcache, btab, ctx, part_o, part_ml);
  attn_combine_xb<<<B_ * HKV_, 256, 0, stream>>>(part_o, part_ml, XBhi, XBlo);
  gemm_mfma<<<dim3(O_ROWS / 128, KSO), 256, 0, stream>>>(
      Wo, Wo, Wo, XBhi, XBlo, O_ROWS, O_ROWS, O_ROWS, HID_ / KSO, HID_ / KSO / 32, part3);
  reduce_out_t<<<O_ROWS / 64, 256, 0, stream>>>(part3, out);
}

// Round 12
// 184.128 us; speedup vs baseline: 1.2171x; 1.1580x over previous
//
#include <hip/hip_runtime.h>

#define B_    64
#define HID_  4096
#define HQ_   32
#define HKV_  8
#define D_    128
#define BS_   16
#define MAXB_ 64

#define KS      16                // K-split both GEMMs (chunk 256, 8 steps)
#define KCHUNK  (HID_ / KS)       // 256
#define QKV_ROWS 6144
#define O_ROWS   4096
#define SPLITS  8

#define REGION_SZ ((size_t)KS * QKV_ROWS * 64)    // 6.3M floats (max overlay)
#define QKVF_SZ  ((size_t)64 * 6144)
#define XB_SZ    ((size_t)HID_ * 64)

typedef __attribute__((ext_vector_type(8))) short bf16x8;
typedef __attribute__((ext_vector_type(4))) float f32x4;

__device__ inline unsigned short f2bf(float x) {
  union { float f; unsigned u; } v; v.f = x;
  unsigned r = v.u + 0x7fff + ((v.u >> 16) & 1);   // RNE
  return (unsigned short)(r >> 16);
}
__device__ inline float bf2f(unsigned short h) {
  union { float f; unsigned u; } v; v.u = ((unsigned)h) << 16; return v.f;
}

// ---------------------------------------------------------------------------
// Convert X [64][HID] fp32 -> fragment-contiguous bf16 hi/lo.
// ---------------------------------------------------------------------------
__global__ __launch_bounds__(256) void convert_x(
    const float* __restrict__ X, unsigned short* __restrict__ XBhi,
    unsigned short* __restrict__ XBlo)
{
  int idx = blockIdx.x * 256 + threadIdx.x;   // 0..32767
  int kg = idx >> 6, b = idx & 63;
  const float* xp = X + (size_t)b * HID_ + kg * 8;
  float4 a = *(const float4*)xp, c = *(const float4*)(xp + 4);
  float xs[8] = {a.x, a.y, a.z, a.w, c.x, c.y, c.z, c.w};
  unsigned short hi[8], lo[8];
  #pragma unroll
  for (int j = 0; j < 8; ++j) {
    hi[j] = f2bf(xs[j]);
    lo[j] = f2bf(xs[j] - bf2f(hi[j]));
  }
  *(uint4*)(XBhi + (size_t)idx * 8) = *(const uint4*)hi;
  *(uint4*)(XBlo + (size_t)idx * 8) = *(const uint4*)lo;
}

// ---------------------------------------------------------------------------
// Split-bf16 MFMA skinny GEMM partial (round-8 version, KS=16).
// Wave = 32 rows (2 row-tiles) x 64 batches (4 col-tiles of 16x16x32).
// A (W) fp32 direct from global, cvt in-register; B from XB (L2).
// 3 MFMA: hi*hi + lo*hi + hi*lo. part[ks][row][64batch].
// ---------------------------------------------------------------------------
__global__ __launch_bounds__(256, 4) void gemm_mfma(
    const float* __restrict__ W0, const float* __restrict__ W1,
    const float* __restrict__ W2,
    const unsigned short* __restrict__ XBhi,
    const unsigned short* __restrict__ XBlo,
    int split1, int split2, int rows_total, float* __restrict__ part)
{
  const int tid = threadIdx.x;
  const int l   = tid & 63;
  const int w   = tid >> 6;
  const int r0  = blockIdx.x * 128 + w * 32;
  const int k0  = blockIdx.y * KCHUNK;

  const float* W; int rloc;
  if (r0 < split1)      { W = W0; rloc = r0; }
  else if (r0 < split2) { W = W1; rloc = r0 - split1; }
  else                  { W = W2; rloc = r0 - split2; }

  const int lm = l & 15;
  const int lk = l >> 4;

  const float* wp0 = W + (size_t)(rloc + lm) * HID_ + k0 + lk * 8;
  const float* wp1 = wp0 + (size_t)16 * HID_;
  const unsigned short* bh = XBhi + ((size_t)(k0 / 8 + lk) * 64 + lm) * 8;
  const unsigned short* bl = XBlo + ((size_t)(k0 / 8 + lk) * 64 + lm) * 8;

  f32x4 acc[2][4];
  #pragma unroll
  for (int rt = 0; rt < 2; ++rt)
    #pragma unroll
    for (int ct = 0; ct < 4; ++ct)
      #pragma unroll
      for (int i = 0; i < 4; ++i) acc[rt][ct][i] = 0.f;

  #pragma unroll 2
  for (int ks = 0; ks < KCHUNK / 32; ++ks) {
    bf16x8 Bh[4], Bl[4];
    #pragma unroll
    for (int ct = 0; ct < 4; ++ct) {
      Bh[ct] = *(const bf16x8*)(bh + (size_t)ks * 2048 + ct * 128);
      Bl[ct] = *(const bf16x8*)(bl + (size_t)ks * 2048 + ct * 128);
    }
    #pragma unroll
    for (int rt = 0; rt < 2; ++rt) {
      const float* wp = (rt ? wp1 : wp0) + ks * 32;
      float4 a0 = *(const float4*)wp;
      float4 a1 = *(const float4*)(wp + 4);
      float xs[8] = {a0.x, a0.y, a0.z, a0.w, a1.x, a1.y, a1.z, a1.w};
      bf16x8 Ah, Al;
      #pragma unroll
      for (int j = 0; j < 8; ++j) {
        unsigned short h = f2bf(xs[j]);
        Ah[j] = (short)h;
        Al[j] = (short)f2bf(xs[j] - bf2f(h));
      }
      #pragma unroll
      for (int ct = 0; ct < 4; ++ct) {
        acc[rt][ct] = __builtin_amdgcn_mfma_f32_16x16x32_bf16(Ah, Bh[ct], acc[rt][ct], 0, 0, 0);
        acc[rt][ct] = __builtin_amdgcn_mfma_f32_16x16x32_bf16(Al, Bh[ct], acc[rt][ct], 0, 0, 0);
        acc[rt][ct] = __builtin_amdgcn_mfma_f32_16x16x32_bf16(Ah, Bl[ct], acc[rt][ct], 0, 0, 0);
      }
    }
  }

  #pragma unroll
  for (int rt = 0; rt < 2; ++rt)
    #pragma unroll
    for (int ct = 0; ct < 4; ++ct) {
      int row = r0 + rt * 16 + lk * 4;
      int bat = ct * 16 + lm;
      #pragma unroll
      for (int i = 0; i < 4; ++i)
        part[((size_t)blockIdx.y * rows_total + row + i) * 64 + bat] = acc[rt][ct][i];
    }
}

// ---------------------------------------------------------------------------
// Sum K-split partials + RoPE (half-split). q scaled by 1/sqrt(D).
// qkvf layout: q[64][32][128] | k[64][8][128] | v[64][8][128]
// ---------------------------------------------------------------------------
__global__ __launch_bounds__(256) void reduce_rope(
    const float* __restrict__ part, const float* __restrict__ cosT,
    const float* __restrict__ sinT, const int* __restrict__ positions,
    float* __restrict__ qkvf)
{
  const int bb  = threadIdx.x & 63;
  const int cid = blockIdx.x * 4 + (threadIdx.x >> 6);
  const int pos = positions[bb];

  if (cid < 2048) {
    const int hq = cid >> 6, d0 = cid & 63;
    const int r1 = hq * 128 + d0;
    float x1 = 0.f, x2 = 0.f;
    #pragma unroll 8
    for (int ks = 0; ks < KS; ++ks) {
      x1 += part[((size_t)ks * QKV_ROWS + r1) * 64 + bb];
      x2 += part[((size_t)ks * QKV_ROWS + r1 + 64) * 64 + bb];
    }
    float c = cosT[pos * 64 + d0], s = sinT[pos * 64 + d0];
    const float scale = 0.08838834764831843f;
    qkvf[(size_t)(bb * 32 + hq) * 128 + d0]      = (x1 * c - x2 * s) * scale;
    qkvf[(size_t)(bb * 32 + hq) * 128 + d0 + 64] = (x2 * c + x1 * s) * scale;
  } else if (cid < 2560) {
    const int c2 = cid - 2048;
    const int kh = c2 >> 6, d0 = c2 & 63;
    const int r1 = 4096 + kh * 128 + d0;
    float x1 = 0.f, x2 = 0.f;
    #pragma unroll 8
    for (int ks = 0; ks < KS; ++ks) {
      x1 += part[((size_t)ks * QKV_ROWS + r1) * 64 + bb];
      x2 += part[((size_t)ks * QKV_ROWS + r1 + 64) * 64 + bb];
    }
    float c = cosT[pos * 64 + d0], s = sinT[pos * 64 + d0];
    qkvf[262144 + (size_t)(bb * 8 + kh) * 128 + d0]      = x1 * c - x2 * s;
    qkvf[262144 + (size_t)(bb * 8 + kh) * 128 + d0 + 64] = x2 * c + x1 * s;
  } else {
    const int c2 = cid - 2560;
    const int kh = c2 >> 6, d0 = c2 & 63;
    const int r1 = 5120 + kh * 128 + d0;
    float x1 = 0.f, x2 = 0.f;
    #pragma unroll 8
    for (int ks = 0; ks < KS; ++ks) {
      x1 += part[((size_t)ks * QKV_ROWS + r1) * 64 + bb];
      x2 += part[((size_t)ks * QKV_ROWS + r1 + 64) * 64 + bb];
    }
    qkvf[327680 + (size_t)(bb * 8 + kh) * 128 + d0]      = x1;
    qkvf[327680 + (size_t)(bb * 8 + kh) * 128 + d0 + 64] = x2;
  }
}

// ---------------------------------------------------------------------------
// Single-pass ONLINE-softmax flash-decode split. Branch-free inner loop:
// btab hoisted to LDS, K+V loads issued together (2x MLP), last-token patch
// hoisted out (only split 7 contains ctx-1 since ctx>=512).
// Merge: halves in a wave via shfl_xor(32), waves via 8KB LDS.
// Emits unnormalized partials (m, l, sum pV) like before.
// ---------------------------------------------------------------------------
__global__ __launch_bounds__(256, 4) void attn_split(
    const float* __restrict__ qkvf, const float* __restrict__ kcache,
    const float* __restrict__ vcache, const int* __restrict__ btab,
    const int* __restrict__ ctxlen,
    float* __restrict__ part_o,   // [B*HKV*SPLITS][4][128]
    float* __restrict__ part_ml)  // [B*HKV*SPLITS][4][2]
{
  const int bid = blockIdx.x;
  const int s   = bid & (SPLITS - 1);
  const int bh  = bid >> 3;
  const int b = bh >> 3, h = bh & 7;
  const int ctx   = ctxlen[b];
  const int chunk = (ctx + SPLITS - 1) / SPLITS;
  const int t0 = s * chunk;
  const int t1 = min(ctx, t0 + chunk);
  const int last = ctx - 1;
  const int tEnd = min(t1, last);     // exclude last token from cached loop

  const int tid  = threadIdx.x;
  const int half = tid >> 5;          // 0..7
  const int d4   = tid & 31;

  __shared__ int   sblk[16];
  __shared__ float wm[4][4], wl[4][4];
  __shared__ float wacc[4][4][128];

  const int blk0 = t0 >> 4;
  if (tid < 16) {
    int ib = blk0 + tid;
    sblk[tid] = (ib < MAXB_) ? btab[b * MAXB_ + ib] : 0;
  }
  __syncthreads();

  float4 qf[4];
  #pragma unroll
  for (int g = 0; g < 4; ++g)
    qf[g] = *(const float4*)(qkvf + (size_t)(b * 32 + h * 4 + g) * 128 + d4 * 4);

  float m[4], l[4], acc[4][4];
  #pragma unroll
  for (int g = 0; g < 4; ++g) {
    m[g] = -1e30f; l[g] = 0.f;
    #pragma unroll
    for (int j = 0; j < 4; ++j) acc[g][j] = 0.f;
  }

  // ---- single pass, branch-free
  for (int t = t0 + half; t < tEnd; t += 8) {
    int slot = sblk[(t >> 4) - blk0] * BS_ + (t & 15);
    const float* base = kcache + ((size_t)slot * HKV_ + h) * D_ + d4 * 4;
    const float* vbas = vcache + ((size_t)slot * HKV_ + h) * D_ + d4 * 4;
    float4 kv = *(const float4*)base;
    float4 vv = *(const float4*)vbas;

    float p0 = qf[0].x * kv.x + qf[0].y * kv.y + qf[0].z * kv.z + qf[0].w * kv.w;
    float p1 = qf[1].x * kv.x + qf[1].y * kv.y + qf[1].z * kv.z + qf[1].w * kv.w;
    float p2 = qf[2].x * kv.x + qf[2].y * kv.y + qf[2].z * kv.z + qf[2].w * kv.w;
    float p3 = qf[3].x * kv.x + qf[3].y * kv.y + qf[3].z * kv.z + qf[3].w * kv.w;
    #pragma unroll
    for (int mm = 16; mm >= 1; mm >>= 1) {
      p0 += __shfl_xor(p0, mm);
      p1 += __shfl_xor(p1, mm);
      p2 += __shfl_xor(p2, mm);
      p3 += __shfl_xor(p3, mm);
    }
    float pg[4] = {p0, p1, p2, p3};
    #pragma unroll
    for (int g = 0; g < 4; ++g) {
      float nm = fmaxf(m[g], pg[g]);
      float sc = __expf(m[g] - nm);
      float pe = __expf(pg[g] - nm);
      l[g] = l[g] * sc + pe;
      acc[g][0] = acc[g][0] * sc + pe * vv.x;
      acc[g][1] = acc[g][1] * sc + pe * vv.y;
      acc[g][2] = acc[g][2] * sc + pe * vv.z;
      acc[g][3] = acc[g][3] * sc + pe * vv.w;
      m[g] = nm;
    }
  }

  // ---- last token (fresh roped k/v), only in split 7's range
  if (t1 > last && half == ((last - t0) & 7)) {
    const float* kp = qkvf + 262144 + (size_t)(b * 8 + h) * 128 + d4 * 4;
    const float* vp = qkvf + 327680 + (size_t)(b * 8 + h) * 128 + d4 * 4;
    float4 kv = *(const float4*)kp;
    float4 vv = *(const float4*)vp;
    float p0 = qf[0].x * kv.x + qf[0].y * kv.y + qf[0].z * kv.z + qf[0].w * kv.w;
    float p1 = qf[1].x * kv.x + qf[1].y * kv.y + qf[1].z * kv.z + qf[1].w * kv.w;
    float p2 = qf[2].x * kv.x + qf[2].y * kv.y + qf[2].z * kv.z + qf[2].w * kv.w;
    float p3 = qf[3].x * kv.x + qf[3].y * kv.y + qf[3].z * kv.z + qf[3].w * kv.w;
    #pragma unroll
    for (int mm = 16; mm >= 1; mm >>= 1) {
      p0 += __shfl_xor(p0, mm);
      p1 += __shfl_xor(p1, mm);
      p2 += __shfl_xor(p2, mm);
      p3 += __shfl_xor(p3, mm);
    }
    float pg[4] = {p0, p1, p2, p3};
    #pragma unroll
    for (int g = 0; g < 4; ++g) {
      float nm = fmaxf(m[g], pg[g]);
      float sc = __expf(m[g] - nm);
      float pe = __expf(pg[g] - nm);
      l[g] = l[g] * sc + pe;
      acc[g][0] = acc[g][0] * sc + pe * vv.x;
      acc[g][1] = acc[g][1] * sc + pe * vv.y;
      acc[g][2] = acc[g][2] * sc + pe * vv.z;
      acc[g][3] = acc[g][3] * sc + pe * vv.w;
      m[g] = nm;
    }
  }

  // ---- merge half-pairs within wave (lane <-> lane^32 share d4)
  #pragma unroll
  for (int g = 0; g < 4; ++g) {
    float om = __shfl_xor(m[g], 32);
    float ol = __shfl_xor(l[g], 32);
    float M  = fmaxf(m[g], om);
    float s0 = __expf(m[g] - M);
    float s1 = __expf(om - M);
    l[g] = l[g] * s0 + ol * s1;
    #pragma unroll
    for (int j = 0; j < 4; ++j) {
      float oa = __shfl_xor(acc[g][j], 32);
      acc[g][j] = acc[g][j] * s0 + oa * s1;
    }
    m[g] = M;
  }
  if ((tid & 32) == 0) {
    int wv = tid >> 6;
    if (d4 == 0) {
      #pragma unroll
      for (int g = 0; g < 4; ++g) { wm[wv][g] = m[g]; wl[wv][g] = l[g]; }
    }
    #pragma unroll
    for (int g = 0; g < 4; ++g)
      #pragma unroll
      for (int j = 0; j < 4; ++j)
        wacc[wv][g][d4 * 4 + j] = acc[g][j];
  }
  __syncthreads();

  // ---- merge 4 waves, emit partial (m*, l*, unnormalized o*)
  for (int idx = tid; idx < 512; idx += 256) {
    int g = idx >> 7, d = idx & 127;
    float M4 = fmaxf(fmaxf(wm[0][g], wm[1][g]), fmaxf(wm[2][g], wm[3][g]));
    float e0 = __expf(wm[0][g] - M4), e1 = __expf(wm[1][g] - M4);
    float e2 = __expf(wm[2][g] - M4), e3 = __expf(wm[3][g] - M4);
    float num = wacc[0][g][d] * e0 + wacc[1][g][d] * e1
              + wacc[2][g][d] * e2 + wacc[3][g][d] * e3;
    part_o[(size_t)bid * 512 + idx] = num;
    if (d == 0) {
      float lt = wl[0][g] * e0 + wl[1][g] * e1 + wl[2][g] * e2 + wl[3][g] * e3;
      part_ml[(size_t)bid * 8 + g * 2]     = M4;
      part_ml[(size_t)bid * 8 + g * 2 + 1] = lt;
    }
  }
}

// ---------------------------------------------------------------------------
// Combine split partials AND emit bf16 hi/lo XB layout for the O-GEMM.
// ---------------------------------------------------------------------------
__global__ __launch_bounds__(256) void attn_combine_xb(
    const float* __restrict__ part_o, const float* __restrict__ part_ml,
    unsigned short* __restrict__ XBhi, unsigned short* __restrict__ XBlo)
{
  const int bh = blockIdx.x;            // 0..511
  const int b = bh >> 3, h = bh & 7;
  const int tid = threadIdx.x;

  __shared__ float Sg[SPLITS][4];
  __shared__ float Dg[4];

  if (tid < 32) {
    int s = tid >> 2, g = tid & 3;
    float m = part_ml[((size_t)bh * SPLITS + s) * 8 + g * 2];
    float l = part_ml[((size_t)bh * SPLITS + s) * 8 + g * 2 + 1];
    float M = m;
    #pragma unroll
    for (int k = 4; k <= 16; k <<= 1) M = fmaxf(M, __shfl_xor(M, k));
    float scl = __expf(m - M);
    float dl = l * scl;
    #pragma unroll
    for (int k = 4; k <= 16; k <<= 1) dl += __shfl_xor(dl, k);
    Sg[s][g] = scl;
    if (s == 0) Dg[g] = dl;
  }
  __syncthreads();

  for (int idx = tid; idx < 512; idx += 256) {
    int g = idx >> 7, d = idx & 127;
    float num = 0.f;
    #pragma unroll
    for (int s = 0; s < SPLITS; ++s)
      num += Sg[s][g] * part_o[((size_t)bh * SPLITS + s) * 512 + idx];
    float val = num / Dg[g];
    int col = (h * 4 + g) * 128 + d;
    int kg = col >> 3, j = col & 7;
    unsigned short hi = f2bf(val);
    unsigned short lo = f2bf(val - bf2f(hi));
    XBhi[((size_t)kg * 64 + b) * 8 + j] = hi;
    XBlo[((size_t)kg * 64 + b) * 8 + j] = lo;
  }
}

// ---------------------------------------------------------------------------
// Sum KS partials of O-GEMM ([ks][row][batch]) -> out[b][row] via LDS
// transpose, coalesced both sides.
// ---------------------------------------------------------------------------
__global__ __launch_bounds__(256) void reduce_out_t(
    const float* __restrict__ part, float* __restrict__ out)
{
  __shared__ float t[64][65];
  const int i0 = blockIdx.x * 64;
  const int lane = threadIdx.x & 63, q = threadIdx.x >> 6;

  #pragma unroll
  for (int rr = q; rr < 64; rr += 4) {
    float s = 0.f;
    #pragma unroll 8
    for (int ks = 0; ks < KS; ++ks)
      s += part[((size_t)ks * O_ROWS + i0 + rr) * 64 + lane];
    t[rr][lane] = s;
  }
  __syncthreads();
  #pragma unroll
  for (int rr = q; rr < 64; rr += 4)
    out[(size_t)rr * O_ROWS + i0 + lane] = t[lane][rr];
}

// ---------------------------------------------------------------------------
extern "C" void kernel_launch(void* const* d_in, const int* in_sizes, int n_in,
                              void* d_out, int out_size, void* d_ws, size_t ws_size,
                              hipStream_t stream)
{
  (void)in_sizes; (void)n_in; (void)out_size; (void)ws_size;
  const float* hidden    = (const float*)d_in[0];
  const int*   positions = (const int*)d_in[1];
  const float* cosT      = (const float*)d_in[2];
  const float* sinT      = (const float*)d_in[3];
  const float* kcache    = (const float*)d_in[4];
  const float* vcache    = (const float*)d_in[5];
  const int*   btab      = (const int*)d_in[7];
  const int*   ctx       = (const int*)d_in[8];
  const float* Wq        = (const float*)d_in[9];
  const float* Wk        = (const float*)d_in[10];
  const float* Wv        = (const float*)d_in[11];
  const float* Wo        = (const float*)d_in[12];
  float* out = (float*)d_out;

  float* ws      = (float*)d_ws;
  float* region  = ws;                       // reused 3x
  float* qkvf    = region + REGION_SZ;
  unsigned short* XBhi = (unsigned short*)(qkvf + QKVF_SZ);
  unsigned short* XBlo = XBhi + XB_SZ;
  float* part1   = region;                                     // phase 1
  float* part_o  = region;                                     // phase 2
  float* part_ml = region + (size_t)B_ * HKV_ * SPLITS * 512;
  float* part3   = region;                                     // phase 3

  convert_x<<<128, 256, 0, stream>>>(hidden, XBhi, XBlo);
  gemm_mfma<<<dim3(QKV_ROWS / 128, KS), 256, 0, stream>>>(
      Wq, Wk, Wv, XBhi, XBlo, 4096, 5120, QKV_ROWS, part1);
  reduce_rope<<<768, 256, 0, stream>>>(part1, cosT, sinT, positions, qkvf);
  attn_split<<<B_ * HKV_ * SPLITS, 256, 0, stream>>>(
      qkvf, kcache, vcache, btab, ctx, part_o, part_ml);
  attn_combine_xb<<<B_ * HKV_, 256, 0, stream>>>(part_o, part_ml, XBhi, XBlo);
  gemm_mfma<<<dim3(O_ROWS / 128, KS), 256, 0, stream>>>(
      Wo, Wo, Wo, XBhi, XBlo, O_ROWS, O_ROWS, O_ROWS, part3);
  reduce_out_t<<<O_ROWS / 64, 256, 0, stream>>>(part3, out);
}

// Round 13
// 183.626 us; speedup vs baseline: 1.2204x; 1.0027x over previous
//
#include <hip/hip_runtime.h>
#include <hip/hip_bf16.h>

#define B_    64
#define HID_  4096
#define HQ_   32
#define HKV_  8
#define D_    128
#define BS_   16
#define MAXB_ 64

#define KS      16                // K-split both GEMMs (chunk 256, 8 steps)
#define KCHUNK  (HID_ / KS)       // 256
#define QKV_ROWS 6144
#define O_ROWS   4096
#define SPLITS  8

#define REGION_SZ ((size_t)KS * QKV_ROWS * 64)    // 6.3M floats (max overlay)
#define QKVF_SZ  ((size_t)64 * 6144)
#define XB_SZ    ((size_t)HID_ * 64)

typedef __attribute__((ext_vector_type(8))) short bf16x8;
typedef __attribute__((ext_vector_type(4))) float f32x4;

// Native bf16 conversion: compiler pairs these into v_cvt_pk_bf16_f32.
__device__ inline unsigned short f2bf(float x) {
  __hip_bfloat16 h = __float2bfloat16(x);           // HW RNE
  union { __hip_bfloat16 b; unsigned short u; } v; v.b = h;
  return v.u;
}
__device__ inline float bf2f(unsigned short h) {
  union { float f; unsigned u; } v; v.u = ((unsigned)h) << 16;  // 1 shift
  return v.f;
}

// ---------------------------------------------------------------------------
// Convert X [64][HID] fp32 -> fragment-contiguous bf16 hi/lo.
// ---------------------------------------------------------------------------
__global__ __launch_bounds__(256) void convert_x(
    const float* __restrict__ X, unsigned short* __restrict__ XBhi,
    unsigned short* __restrict__ XBlo)
{
  int idx = blockIdx.x * 256 + threadIdx.x;   // 0..32767
  int kg = idx >> 6, b = idx & 63;
  const float* xp = X + (size_t)b * HID_ + kg * 8;
  float4 a = *(const float4*)xp, c = *(const float4*)(xp + 4);
  float xs[8] = {a.x, a.y, a.z, a.w, c.x, c.y, c.z, c.w};
  unsigned short hi[8], lo[8];
  #pragma unroll
  for (int j = 0; j < 8; ++j) {
    hi[j] = f2bf(xs[j]);
    lo[j] = f2bf(xs[j] - bf2f(hi[j]));
  }
  *(uint4*)(XBhi + (size_t)idx * 8) = *(const uint4*)hi;
  *(uint4*)(XBlo + (size_t)idx * 8) = *(const uint4*)lo;
}

// ---------------------------------------------------------------------------
// Split-bf16 MFMA skinny GEMM partial (r8 geometry, KS=16, native cvt).
// Wave = 32 rows (2 row-tiles) x 64 batches (4 col-tiles of 16x16x32).
// A (W) fp32 direct from global, cvt in-register (v_cvt_pk_bf16_f32 path);
// B from XB (L2). 3 MFMA: hi*hi + lo*hi + hi*lo. part[ks][row][64batch].
// ---------------------------------------------------------------------------
__global__ __launch_bounds__(256, 4) void gemm_mfma(
    const float* __restrict__ W0, const float* __restrict__ W1,
    const float* __restrict__ W2,
    const unsigned short* __restrict__ XBhi,
    const unsigned short* __restrict__ XBlo,
    int split1, int split2, int rows_total, float* __restrict__ part)
{
  const int tid = threadIdx.x;
  const int l   = tid & 63;
  const int w   = tid >> 6;
  const int r0  = blockIdx.x * 128 + w * 32;
  const int k0  = blockIdx.y * KCHUNK;

  const float* W; int rloc;
  if (r0 < split1)      { W = W0; rloc = r0; }
  else if (r0 < split2) { W = W1; rloc = r0 - split1; }
  else                  { W = W2; rloc = r0 - split2; }

  const int lm = l & 15;
  const int lk = l >> 4;

  const float* wp0 = W + (size_t)(rloc + lm) * HID_ + k0 + lk * 8;
  const float* wp1 = wp0 + (size_t)16 * HID_;
  const unsigned short* bh = XBhi + ((size_t)(k0 / 8 + lk) * 64 + lm) * 8;
  const unsigned short* bl = XBlo + ((size_t)(k0 / 8 + lk) * 64 + lm) * 8;

  f32x4 acc[2][4];
  #pragma unroll
  for (int rt = 0; rt < 2; ++rt)
    #pragma unroll
    for (int ct = 0; ct < 4; ++ct)
      #pragma unroll
      for (int i = 0; i < 4; ++i) acc[rt][ct][i] = 0.f;

  #pragma unroll 2
  for (int ks = 0; ks < KCHUNK / 32; ++ks) {
    bf16x8 Bh[4], Bl[4];
    #pragma unroll
    for (int ct = 0; ct < 4; ++ct) {
      Bh[ct] = *(const bf16x8*)(bh + (size_t)ks * 2048 + ct * 128);
      Bl[ct] = *(const bf16x8*)(bl + (size_t)ks * 2048 + ct * 128);
    }
    #pragma unroll
    for (int rt = 0; rt < 2; ++rt) {
      const float* wp = (rt ? wp1 : wp0) + ks * 32;
      float4 a0 = *(const float4*)wp;
      float4 a1 = *(const float4*)(wp + 4);
      float xs[8] = {a0.x, a0.y, a0.z, a0.w, a1.x, a1.y, a1.z, a1.w};
      bf16x8 Ah, Al;
      #pragma unroll
      for (int j = 0; j < 8; ++j) {
        unsigned short h = f2bf(xs[j]);
        Ah[j] = (short)h;
        Al[j] = (short)f2bf(xs[j] - bf2f(h));
      }
      #pragma unroll
      for (int ct = 0; ct < 4; ++ct) {
        acc[rt][ct] = __builtin_amdgcn_mfma_f32_16x16x32_bf16(Ah, Bh[ct], acc[rt][ct], 0, 0, 0);
        acc[rt][ct] = __builtin_amdgcn_mfma_f32_16x16x32_bf16(Al, Bh[ct], acc[rt][ct], 0, 0, 0);
        acc[rt][ct] = __builtin_amdgcn_mfma_f32_16x16x32_bf16(Ah, Bl[ct], acc[rt][ct], 0, 0, 0);
      }
    }
  }

  #pragma unroll
  for (int rt = 0; rt < 2; ++rt)
    #pragma unroll
    for (int ct = 0; ct < 4; ++ct) {
      int row = r0 + rt * 16 + lk * 4;
      int bat = ct * 16 + lm;
      #pragma unroll
      for (int i = 0; i < 4; ++i)
        part[((size_t)blockIdx.y * rows_total + row + i) * 64 + bat] = acc[rt][ct][i];
    }
}

// ---------------------------------------------------------------------------
// Sum K-split partials + RoPE (half-split). q scaled by 1/sqrt(D).
// qkvf layout: q[64][32][128] | k[64][8][128] | v[64][8][128]
// ---------------------------------------------------------------------------
__global__ __launch_bounds__(256) void reduce_rope(
    const float* __restrict__ part, const float* __restrict__ cosT,
    const float* __restrict__ sinT, const int* __restrict__ positions,
    float* __restrict__ qkvf)
{
  const int bb  = threadIdx.x & 63;
  const int cid = blockIdx.x * 4 + (threadIdx.x >> 6);
  const int pos = positions[bb];

  if (cid < 2048) {
    const int hq = cid >> 6, d0 = cid & 63;
    const int r1 = hq * 128 + d0;
    float x1 = 0.f, x2 = 0.f;
    #pragma unroll 8
    for (int ks = 0; ks < KS; ++ks) {
      x1 += part[((size_t)ks * QKV_ROWS + r1) * 64 + bb];
      x2 += part[((size_t)ks * QKV_ROWS + r1 + 64) * 64 + bb];
    }
    float c = cosT[pos * 64 + d0], s = sinT[pos * 64 + d0];
    const float scale = 0.08838834764831843f;
    qkvf[(size_t)(bb * 32 + hq) * 128 + d0]      = (x1 * c - x2 * s) * scale;
    qkvf[(size_t)(bb * 32 + hq) * 128 + d0 + 64] = (x2 * c + x1 * s) * scale;
  } else if (cid < 2560) {
    const int c2 = cid - 2048;
    const int kh = c2 >> 6, d0 = c2 & 63;
    const int r1 = 4096 + kh * 128 + d0;
    float x1 = 0.f, x2 = 0.f;
    #pragma unroll 8
    for (int ks = 0; ks < KS; ++ks) {
      x1 += part[((size_t)ks * QKV_ROWS + r1) * 64 + bb];
      x2 += part[((size_t)ks * QKV_ROWS + r1 + 64) * 64 + bb];
    }
    float c = cosT[pos * 64 + d0], s = sinT[pos * 64 + d0];
    qkvf[262144 + (size_t)(bb * 8 + kh) * 128 + d0]      = x1 * c - x2 * s;
    qkvf[262144 + (size_t)(bb * 8 + kh) * 128 + d0 + 64] = x2 * c + x1 * s;
  } else {
    const int c2 = cid - 2560;
    const int kh = c2 >> 6, d0 = c2 & 63;
    const int r1 = 5120 + kh * 128 + d0;
    float x1 = 0.f, x2 = 0.f;
    #pragma unroll 8
    for (int ks = 0; ks < KS; ++ks) {
      x1 += part[((size_t)ks * QKV_ROWS + r1) * 64 + bb];
      x2 += part[((size_t)ks * QKV_ROWS + r1 + 64) * 64 + bb];
    }
    qkvf[327680 + (size_t)(bb * 8 + kh) * 128 + d0]      = x1;
    qkvf[327680 + (size_t)(bb * 8 + kh) * 128 + d0 + 64] = x2;
  }
}

// ---------------------------------------------------------------------------
// Single-pass online-softmax flash-decode split (r12 version).
// ---------------------------------------------------------------------------
__global__ __launch_bounds__(256, 4) void attn_split(
    const float* __restrict__ qkvf, const float* __restrict__ kcache,
    const float* __restrict__ vcache, const int* __restrict__ btab,
    const int* __restrict__ ctxlen,
    float* __restrict__ part_o,   // [B*HKV*SPLITS][4][128]
    float* __restrict__ part_ml)  // [B*HKV*SPLITS][4][2]
{
  const int bid = blockIdx.x;
  const int s   = bid & (SPLITS - 1);
  const int bh  = bid >> 3;
  const int b = bh >> 3, h = bh & 7;
  const int ctx   = ctxlen[b];
  const int chunk = (ctx + SPLITS - 1) / SPLITS;
  const int t0 = s * chunk;
  const int t1 = min(ctx, t0 + chunk);
  const int last = ctx - 1;
  const int tEnd = min(t1, last);

  const int tid  = threadIdx.x;
  const int half = tid >> 5;
  const int d4   = tid & 31;

  __shared__ int   sblk[16];
  __shared__ float wm[4][4], wl[4][4];
  __shared__ float wacc[4][4][128];

  const int blk0 = t0 >> 4;
  if (tid < 16) {
    int ib = blk0 + tid;
    sblk[tid] = (ib < MAXB_) ? btab[b * MAXB_ + ib] : 0;
  }
  __syncthreads();

  float4 qf[4];
  #pragma unroll
  for (int g = 0; g < 4; ++g)
    qf[g] = *(const float4*)(qkvf + (size_t)(b * 32 + h * 4 + g) * 128 + d4 * 4);

  float m[4], l[4], acc[4][4];
  #pragma unroll
  for (int g = 0; g < 4; ++g) {
    m[g] = -1e30f; l[g] = 0.f;
    #pragma unroll
    for (int j = 0; j < 4; ++j) acc[g][j] = 0.f;
  }

  for (int t = t0 + half; t < tEnd; t += 8) {
    int slot = sblk[(t >> 4) - blk0] * BS_ + (t & 15);
    const float* base = kcache + ((size_t)slot * HKV_ + h) * D_ + d4 * 4;
    const float* vbas = vcache + ((size_t)slot * HKV_ + h) * D_ + d4 * 4;
    float4 kv = *(const float4*)base;
    float4 vv = *(const float4*)vbas;

    float p0 = qf[0].x * kv.x + qf[0].y * kv.y + qf[0].z * kv.z + qf[0].w * kv.w;
    float p1 = qf[1].x * kv.x + qf[1].y * kv.y + qf[1].z * kv.z + qf[1].w * kv.w;
    float p2 = qf[2].x * kv.x + qf[2].y * kv.y + qf[2].z * kv.z + qf[2].w * kv.w;
    float p3 = qf[3].x * kv.x + qf[3].y * kv.y + qf[3].z * kv.z + qf[3].w * kv.w;
    #pragma unroll
    for (int mm = 16; mm >= 1; mm >>= 1) {
      p0 += __shfl_xor(p0, mm);
      p1 += __shfl_xor(p1, mm);
      p2 += __shfl_xor(p2, mm);
      p3 += __shfl_xor(p3, mm);
    }
    float pg[4] = {p0, p1, p2, p3};
    #pragma unroll
    for (int g = 0; g < 4; ++g) {
      float nm = fmaxf(m[g], pg[g]);
      float sc = __expf(m[g] - nm);
      float pe = __expf(pg[g] - nm);
      l[g] = l[g] * sc + pe;
      acc[g][0] = acc[g][0] * sc + pe * vv.x;
      acc[g][1] = acc[g][1] * sc + pe * vv.y;
      acc[g][2] = acc[g][2] * sc + pe * vv.z;
      acc[g][3] = acc[g][3] * sc + pe * vv.w;
      m[g] = nm;
    }
  }

  if (t1 > last && half == ((last - t0) & 7)) {
    const float* kp = qkvf + 262144 + (size_t)(b * 8 + h) * 128 + d4 * 4;
    const float* vp = qkvf + 327680 + (size_t)(b * 8 + h) * 128 + d4 * 4;
    float4 kv = *(const float4*)kp;
    float4 vv = *(const float4*)vp;
    float p0 = qf[0].x * kv.x + qf[0].y * kv.y + qf[0].z * kv.z + qf[0].w * kv.w;
    float p1 = qf[1].x * kv.x + qf[1].y * kv.y + qf[1].z * kv.z + qf[1].w * kv.w;
    float p2 = qf[2].x * kv.x + qf[2].y * kv.y + qf[2].z * kv.z + qf[2].w * kv.w;
    float p3 = qf[3].x * kv.x + qf[3].y * kv.y + qf[3].z * kv.z + qf[3].w * kv.w;
    #pragma unroll
    for (int mm = 16; mm >= 1; mm >>= 1) {
      p0 += __shfl_xor(p0, mm);
      p1 += __shfl_xor(p1, mm);
      p2 += __shfl_xor(p2, mm);
      p3 += __shfl_xor(p3, mm);
    }
    float pg[4] = {p0, p1, p2, p3};
    #pragma unroll
    for (int g = 0; g < 4; ++g) {
      float nm = fmaxf(m[g], pg[g]);
      float sc = __expf(m[g] - nm);
      float pe = __expf(pg[g] - nm);
      l[g] = l[g] * sc + pe;
      acc[g][0] = acc[g][0] * sc + pe * vv.x;
      acc[g][1] = acc[g][1] * sc + pe * vv.y;
      acc[g][2] = acc[g][2] * sc + pe * vv.z;
      acc[g][3] = acc[g][3] * sc + pe * vv.w;
      m[g] = nm;
    }
  }

  #pragma unroll
  for (int g = 0; g < 4; ++g) {
    float om = __shfl_xor(m[g], 32);
    float ol = __shfl_xor(l[g], 32);
    float M  = fmaxf(m[g], om);
    float s0 = __expf(m[g] - M);
    float s1 = __expf(om - M);
    l[g] = l[g] * s0 + ol * s1;
    #pragma unroll
    for (int j = 0; j < 4; ++j) {
      float oa = __shfl_xor(acc[g][j], 32);
      acc[g][j] = acc[g][j] * s0 + oa * s1;
    }
    m[g] = M;
  }
  if ((tid & 32) == 0) {
    int wv = tid >> 6;
    if (d4 == 0) {
      #pragma unroll
      for (int g = 0; g < 4; ++g) { wm[wv][g] = m[g]; wl[wv][g] = l[g]; }
    }
    #pragma unroll
    for (int g = 0; g < 4; ++g)
      #pragma unroll
      for (int j = 0; j < 4; ++j)
        wacc[wv][g][d4 * 4 + j] = acc[g][j];
  }
  __syncthreads();

  for (int idx = tid; idx < 512; idx += 256) {
    int g = idx >> 7, d = idx & 127;
    float M4 = fmaxf(fmaxf(wm[0][g], wm[1][g]), fmaxf(wm[2][g], wm[3][g]));
    float e0 = __expf(wm[0][g] - M4), e1 = __expf(wm[1][g] - M4);
    float e2 = __expf(wm[2][g] - M4), e3 = __expf(wm[3][g] - M4);
    float num = wacc[0][g][d] * e0 + wacc[1][g][d] * e1
              + wacc[2][g][d] * e2 + wacc[3][g][d] * e3;
    part_o[(size_t)bid * 512 + idx] = num;
    if (d == 0) {
      float lt = wl[0][g] * e0 + wl[1][g] * e1 + wl[2][g] * e2 + wl[3][g] * e3;
      part_ml[(size_t)bid * 8 + g * 2]     = M4;
      part_ml[(size_t)bid * 8 + g * 2 + 1] = lt;
    }
  }
}

// ---------------------------------------------------------------------------
// Combine split partials AND emit bf16 hi/lo XB layout for the O-GEMM.
// ---------------------------------------------------------------------------
__global__ __launch_bounds__(256) void attn_combine_xb(
    const float* __restrict__ part_o, const float* __restrict__ part_ml,
    unsigned short* __restrict__ XBhi, unsigned short* __restrict__ XBlo)
{
  const int bh = blockIdx.x;            // 0..511
  const int b = bh >> 3, h = bh & 7;
  const int tid = threadIdx.x;

  __shared__ float Sg[SPLITS][4];
  __shared__ float Dg[4];

  if (tid < 32) {
    int s = tid >> 2, g = tid & 3;
    float m = part_ml[((size_t)bh * SPLITS + s) * 8 + g * 2];
    float l = part_ml[((size_t)bh * SPLITS + s) * 8 + g * 2 + 1];
    float M = m;
    #pragma unroll
    for (int k = 4; k <= 16; k <<= 1) M = fmaxf(M, __shfl_xor(M, k));
    float scl = __expf(m - M);
    float dl = l * scl;
    #pragma unroll
    for (int k = 4; k <= 16; k <<= 1) dl += __shfl_xor(dl, k);
    Sg[s][g] = scl;
    if (s == 0) Dg[g] = dl;
  }
  __syncthreads();

  for (int idx = tid; idx < 512; idx += 256) {
    int g = idx >> 7, d = idx & 127;
    float num = 0.f;
    #pragma unroll
    for (int s = 0; s < SPLITS; ++s)
      num += Sg[s][g] * part_o[((size_t)bh * SPLITS + s) * 512 + idx];
    float val = num / Dg[g];
    int col = (h * 4 + g) * 128 + d;
    int kg = col >> 3, j = col & 7;
    unsigned short hi = f2bf(val);
    unsigned short lo = f2bf(val - bf2f(hi));
    XBhi[((size_t)kg * 64 + b) * 8 + j] = hi;
    XBlo[((size_t)kg * 64 + b) * 8 + j] = lo;
  }
}

// ---------------------------------------------------------------------------
// Sum KS partials of O-GEMM ([ks][row][batch]) -> out[b][row] via LDS
// transpose, coalesced both sides.
// ---------------------------------------------------------------------------
__global__ __launch_bounds__(256) void reduce_out_t(
    const float* __restrict__ part, float* __restrict__ out)
{
  __shared__ float t[64][65];
  const int i0 = blockIdx.x * 64;
  const int lane = threadIdx.x & 63, q = threadIdx.x >> 6;

  #pragma unroll
  for (int rr = q; rr < 64; rr += 4) {
    float s = 0.f;
    #pragma unroll 8
    for (int ks = 0; ks < KS; ++ks)
      s += part[((size_t)ks * O_ROWS + i0 + rr) * 64 + lane];
    t[rr][lane] = s;
  }
  __syncthreads();
  #pragma unroll
  for (int rr = q; rr < 64; rr += 4)
    out[(size_t)rr * O_ROWS + i0 + lane] = t[lane][rr];
}

// ---------------------------------------------------------------------------
extern "C" void kernel_launch(void* const* d_in, const int* in_sizes, int n_in,
                              void* d_out, int out_size, void* d_ws, size_t ws_size,
                              hipStream_t stream)
{
  (void)in_sizes; (void)n_in; (void)out_size; (void)ws_size;
  const float* hidden    = (const float*)d_in[0];
  const int*   positions = (const int*)d_in[1];
  const float* cosT      = (const float*)d_in[2];
  const float* sinT      = (const float*)d_in[3];
  const float* kcache    = (const float*)d_in[4];
  const float* vcache    = (const float*)d_in[5];
  const int*   btab      = (const int*)d_in[7];
  const int*   ctx       = (const int*)d_in[8];
  const float* Wq        = (const float*)d_in[9];
  const float* Wk        = (const float*)d_in[10];
  const float* Wv        = (const float*)d_in[11];
  const float* Wo        = (const float*)d_in[12];
  float* out = (float*)d_out;

  float* ws      = (float*)d_ws;
  float* region  = ws;                       // reused 3x
  float* qkvf    = region + REGION_SZ;
  unsigned short* XBhi = (unsigned short*)(qkvf + QKVF_SZ);
  unsigned short* XBlo = XBhi + XB_SZ;
  float* part1   = region;                                     // phase 1
  float* part_o  = region;                                     // phase 2
  float* part_ml = region + (size_t)B_ * HKV_ * SPLITS * 512;
  float* part3   = region;                                     // phase 3

  convert_x<<<128, 256, 0, stream>>>(hidden, XBhi, XBlo);
  gemm_mfma<<<dim3(QKV_ROWS / 128, KS), 256, 0, stream>>>(
      Wq, Wk, Wv, XBhi, XBlo, 4096, 5120, QKV_ROWS, part1);
  reduce_rope<<<768, 256, 0, stream>>>(part1, cosT, sinT, positions, qkvf);
  attn_split<<<B_ * HKV_ * SPLITS, 256, 0, stream>>>(
      qkvf, kcache, vcache, btab, ctx, part_o, part_ml);
  attn_combine_xb<<<B_ * HKV_, 256, 0, stream>>>(part_o, part_ml, XBhi, XBlo);
  gemm_mfma<<<dim3(O_ROWS / 128, KS), 256, 0, stream>>>(
      Wo, Wo, Wo, XBhi, XBlo, O_ROWS, O_ROWS, O_ROWS, part3);
  reduce_out_t<<<O_ROWS / 64, 256, 0, stream>>>(part3, out);
}